// Round 8
// baseline (127.274 us; speedup 1.0000x reference)
//
#include <hip/hip_runtime.h>
#include <stdint.h>

#define B_ROWS 4096
#define OUTF   1024
#define INF    1024
#define KTOT   3072          // 3 * 1024
#define BN_EPS 1e-5f
#define BM 128
#define BN 128
#define BK 128
#define NSTEP (KTOT / BK)    // 24

typedef short  short8  __attribute__((ext_vector_type(8)));
typedef float  floatx4 __attribute__((ext_vector_type(4)));

struct alignas(8) s4 { short x, y, z, w; };

__device__ __forceinline__ short f2bf(float f) {
  union { float f; uint32_t u; } cv; cv.f = f;
  uint32_t u = cv.u;
  uint32_t r = (u + 0x7fffu + ((u >> 16) & 1u)) >> 16;  // RNE
  return (short)r;
}

__device__ __forceinline__ void load_lds16(const void* g, void* l) {
  __builtin_amdgcn_global_load_lds(
      (const __attribute__((address_space(1))) uint32_t*)(uintptr_t)g,
      (__attribute__((address_space(3))) uint32_t*)(uint32_t)(uintptr_t)l,
      16, 0, 0);
}

// ---- 1. prep: x -> bf16 {x,x^2,x^3} (Xb), c1|c2|c3 -> bf16 Wb --------------
// bias is skipped: a per-column constant shifts the batch mean and is
// cancelled exactly by BatchNorm (variance unaffected). [verified R6/R7]
__global__ void prep_all(const float4* __restrict__ x4,
                         const float4* __restrict__ c1, const float4* __restrict__ c2,
                         const float4* __restrict__ c3,
                         short* __restrict__ Xb, short* __restrict__ Wb) {
  int b = blockIdx.x;
  if (b < 4096) {
    int idx = b * 256 + threadIdx.x;           // 1,048,576 float4 of x
    float4 v = x4[idx];
    int row = idx >> 8;
    int c   = (idx & 255) << 2;
    size_t base = (size_t)row * KTOT + c;
    s4 p1 = { f2bf(v.x), f2bf(v.y), f2bf(v.z), f2bf(v.w) };
    float ax = v.x * v.x, ay = v.y * v.y, az = v.z * v.z, aw = v.w * v.w;
    s4 p2 = { f2bf(ax), f2bf(ay), f2bf(az), f2bf(aw) };
    s4 p3 = { f2bf(ax * v.x), f2bf(ay * v.y), f2bf(az * v.z), f2bf(aw * v.w) };
    *(s4*)&Xb[base]        = p1;
    *(s4*)&Xb[base + 1024] = p2;
    *(s4*)&Xb[base + 2048] = p3;
  } else {
    int idx = (b - 4096) * 256 + threadIdx.x;  // 262,144 float4 per weight
    int row = idx >> 8;
    int c   = (idx & 255) << 2;
    size_t base = (size_t)row * KTOT + c;
    float4 a = c1[idx], bb = c2[idx], d = c3[idx];
    s4 p1 = { f2bf(a.x),  f2bf(a.y),  f2bf(a.z),  f2bf(a.w)  };
    s4 p2 = { f2bf(bb.x), f2bf(bb.y), f2bf(bb.z), f2bf(bb.w) };
    s4 p3 = { f2bf(d.x),  f2bf(d.y),  f2bf(d.z),  f2bf(d.w)  };
    *(s4*)&Wb[base]        = p1;
    *(s4*)&Wb[base + 1024] = p2;
    *(s4*)&Wb[base + 2048] = p3;
  }
}

// ---- 2. GEMM 128x128, BK=128, double-buffered LDS, 1-deep prefetch ---------
// 24 K-steps (was 48): each __syncthreads-drain is amortized over 2x compute.
// Prefetch of tile s+1 is issued right after the step-s barrier and lands
// during the ~2000-cyc compute phase; the next barrier's vmcnt(0) drain IS
// the pipeline wait. LDS 2x(32+32) KB = 128 KB, 1 block/CU by construction.
// LDS rows: 128 shorts = 16 chunks of 16 B; physical slot p of row r holds
// logical chunk p ^ (r & 15) -> conflict-free b128 reads [R4: measured 0].
__global__ __launch_bounds__(512, 2) void gemm_poly(
    const short* __restrict__ Xb, const short* __restrict__ Wb,
    float* __restrict__ Y, float* __restrict__ psum, float* __restrict__ psq) {
  __shared__ __align__(16) short As[2][BM * BK];   // 2 x 32 KB
  __shared__ __align__(16) short Bs[2][BN * BK];   // 2 x 32 KB  (128 KB total)
  const int tid  = threadIdx.x;
  const int lane = tid & 63;
  const int wave = tid >> 6;
  const int wr = wave >> 2;            // 0..1 : 64-row half
  const int wc = wave & 3;             // 0..3 : 32-col quarter
  const int lb  = blockIdx.x;
  const int xcd = lb & 7;
  const int sl  = lb >> 3;             // 0..31
  const int bx  = sl & 7;              // col-block 0..7
  const int by  = xcd * 4 + (sl >> 3); // row-strip 0..31
  const int row0 = by * BM;
  const int col0 = bx * BN;
  const short* Ag = Xb + (size_t)row0 * KTOT;
  const short* Bg = Wb + (size_t)col0 * KTOT;
  const int frag_m = lane & 15;
  const int sel = lane >> 4;           // k-quarter within a K=32 sub-step
  floatx4 acc[4][2] = {};

  // staging source offsets: 4 A-chunks + 4 B-chunks per thread (2048 each)
  // chunk c: row r = c >> 4 (16 chunks per 128-short row), slot p = c & 15,
  // logical source chunk l = p ^ (r & 15)
  int off4[4];
  #pragma unroll
  for (int i = 0; i < 4; ++i) {
    int c = tid + i * 512;
    int r = c >> 4, p = c & 15;
    int l = p ^ (r & 15);
    off4[i] = r * KTOT + l * 8;
  }

  // prologue: stage tile 0 into buffer 0
  #pragma unroll
  for (int i = 0; i < 4; ++i) {
    load_lds16(Ag + off4[i], &As[0][(tid + i * 512) * 8]);
    load_lds16(Bg + off4[i], &Bs[0][(tid + i * 512) * 8]);
  }

  for (int step = 0; step < NSTEP; ++step) {
    __syncthreads();                   // drains tile-step loads (vmcnt) + sync
    const int cur = step & 1;
    if (step + 1 < NSTEP) {            // prefetch tile step+1 into other buf
      const int kt = (step + 1) * BK;
      const int nxt = cur ^ 1;
      #pragma unroll
      for (int i = 0; i < 4; ++i) {
        load_lds16(Ag + off4[i] + kt, &As[nxt][(tid + i * 512) * 8]);
        load_lds16(Bg + off4[i] + kt, &Bs[nxt][(tid + i * 512) * 8]);
      }
    }
    #pragma unroll
    for (int s = 0; s < 4; ++s) {      // 4 sub-steps of K=32
      short8 af[4], bfr[2];
      #pragma unroll
      for (int i = 0; i < 4; ++i) {
        int r = wr * 64 + i * 16 + frag_m;
        int p = (s * 4 + sel) ^ (r & 15);
        af[i] = *(const short8*)&As[cur][r * BK + p * 8];
      }
      #pragma unroll
      for (int j = 0; j < 2; ++j) {
        int r = wc * 32 + j * 16 + frag_m;
        int p = (s * 4 + sel) ^ (r & 15);
        bfr[j] = *(const short8*)&Bs[cur][r * BK + p * 8];
      }
      #pragma unroll
      for (int i = 0; i < 4; ++i)
        #pragma unroll
        for (int j = 0; j < 2; ++j)
          acc[i][j] = __builtin_amdgcn_mfma_f32_16x16x32_bf16(af[i], bfr[j], acc[i][j], 0, 0, 0);
    }
  }

  // epilogue: column sum/sumsq partials (no bias), un-normalized Y write
  float* colred = (float*)&As[0][0];   // [wr*256 + {0:sum,128:sq} + col], 2KB
  float sv[2] = {0.f, 0.f}, sq[2] = {0.f, 0.f};
  #pragma unroll
  for (int j = 0; j < 2; ++j)
    #pragma unroll
    for (int i = 0; i < 4; ++i)
      #pragma unroll
      for (int r = 0; r < 4; ++r) {
        float v = acc[i][j][r];
        sv[j] += v; sq[j] += v * v;
      }
  #pragma unroll
  for (int j = 0; j < 2; ++j) {        // fold 4 sel-groups sharing a column
    sv[j] += __shfl_xor(sv[j], 16, 64); sv[j] += __shfl_xor(sv[j], 32, 64);
    sq[j] += __shfl_xor(sq[j], 16, 64); sq[j] += __shfl_xor(sq[j], 32, 64);
  }
  __syncthreads();                     // As[0] now reusable as colred
  if (sel == 0) {
    #pragma unroll
    for (int j = 0; j < 2; ++j) {
      int cc = wc * 32 + j * 16 + frag_m;
      colred[wr * 256 + cc]       = sv[j];
      colred[wr * 256 + 128 + cc] = sq[j];
    }
  }
  // write Y (un-normalized) while colred settles
  const int drow = sel << 2;           // C/D: col=lane&15, row=(lane>>4)*4+r
  #pragma unroll
  for (int j = 0; j < 2; ++j) {
    int gc = col0 + wc * 32 + j * 16 + frag_m;
    #pragma unroll
    for (int i = 0; i < 4; ++i) {
      int gr = row0 + wr * 64 + i * 16 + drow;
      #pragma unroll
      for (int r = 0; r < 4; ++r)
        Y[(size_t)(gr + r) * OUTF + gc] = acc[i][j][r];
    }
  }
  __syncthreads();
  if (tid < BN) {
    psum[(size_t)by * OUTF + col0 + tid] = colred[tid]       + colred[256 + tid];
    psq [(size_t)by * OUTF + col0 + tid] = colred[128 + tid] + colred[384 + tid];
  }
}

// ---- 3. fused finalize + BN apply ------------------------------------------
__global__ void bn_fused(const float* __restrict__ psum, const float* __restrict__ psq,
                         const float* __restrict__ gamma, const float* __restrict__ beta,
                         float* __restrict__ Y) {
  __shared__ float sc[32], sh[32];
  const int c0 = blockIdx.x * 32;
  const int t = threadIdx.x;
  if (t < 32) {
    float s = 0.f, s2 = 0.f;
    #pragma unroll 8
    for (int p = 0; p < 32; ++p) {
      s  += psum[p * OUTF + c0 + t];
      s2 += psq [p * OUTF + c0 + t];
    }
    float mean = s * (1.0f / B_ROWS);
    float var  = s2 * (1.0f / B_ROWS) - mean * mean;
    float scale = gamma[c0 + t] * rsqrtf(var + BN_EPS);
    sc[t] = scale;
    sh[t] = beta[c0 + t] - mean * scale;
  }
  __syncthreads();
  const int f4c = t & 7;          // 8 float4 per 32-col slice
  const int rr  = t >> 3;         // 32 rows per sweep
  const int row0 = blockIdx.y * 256;
  float4* Y4 = (float4*)Y;
  const int cb = f4c * 4;
  float s0 = sc[cb], s1 = sc[cb+1], s2 = sc[cb+2], s3 = sc[cb+3];
  float h0 = sh[cb], h1 = sh[cb+1], h2 = sh[cb+2], h3 = sh[cb+3];
  #pragma unroll
  for (int it = 0; it < 8; ++it) {
    int row = row0 + it * 32 + rr;
    size_t idx = (size_t)row * 256 + (c0 >> 2) + f4c;
    float4 v = Y4[idx];
    v.x = v.x * s0 + h0; v.y = v.y * s1 + h1;
    v.z = v.z * s2 + h2; v.w = v.w * s3 + h3;
    Y4[idx] = v;
  }
}

extern "C" void kernel_launch(void* const* d_in, const int* in_sizes, int n_in,
                              void* d_out, int out_size, void* d_ws, size_t ws_size,
                              hipStream_t stream) {
  const float* x     = (const float*)d_in[0];
  const float* c1    = (const float*)d_in[1];
  const float* c2    = (const float*)d_in[2];
  const float* c3    = (const float*)d_in[3];
  // d_in[4] = bias: unused — per-column constant cancels exactly in BatchNorm
  const float* gamma = (const float*)d_in[5];
  const float* beta  = (const float*)d_in[6];
  float* out = (float*)d_out;
  char* ws = (char*)d_ws;

  short* Xb   = (short*)(ws);                          // 25,165,824 B
  short* Wb   = (short*)(ws + 25165824);               //  6,291,456 B
  float* psum = (float*)(ws + 31457280);               //    128 KB
  float* psq  = (float*)(ws + 31588352);               //    128 KB

  prep_all<<<5120, 256, 0, stream>>>((const float4*)x, (const float4*)c1,
                                     (const float4*)c2, (const float4*)c3,
                                     Xb, Wb);

  gemm_poly<<<256, 512, 0, stream>>>(Xb, Wb, out, psum, psq);

  dim3 bgrid(OUTF / 32, B_ROWS / 256);                 // (32, 16) = 512 blocks
  bn_fused<<<bgrid, 256, 0, stream>>>(psum, psq, gamma, beta, out);
}

// Round 9
// 125.422 us; speedup vs baseline: 1.0148x; 1.0148x over previous
//
#include <hip/hip_runtime.h>
#include <stdint.h>

#define B_ROWS 4096
#define OUTF   1024
#define INF    1024
#define KTOT   3072          // 3 * 1024
#define BN_EPS 1e-5f
#define BM 128
#define BN 128
#define BK 64
#define NSTEP (KTOT / BK)    // 48

typedef short  short8  __attribute__((ext_vector_type(8)));
typedef float  floatx4 __attribute__((ext_vector_type(4)));

struct alignas(8) s4 { short x, y, z, w; };

// s_waitcnt SIMM16 (gfx9/gfx950): vmcnt[3:0]=imm[3:0], expcnt=imm[6:4],
// lgkmcnt=imm[11:8], vmcnt[5:4]=imm[15:14].
#define WAIT_VM8 0x0F78      // vmcnt(8)
#define WAIT_VM4 0x0F74      // vmcnt(4)
#define WAIT_VM0 0x0F70      // vmcnt(0)

__device__ __forceinline__ short f2bf(float f) {
  union { float f; uint32_t u; } cv; cv.f = f;
  uint32_t u = cv.u;
  uint32_t r = (u + 0x7fffu + ((u >> 16) & 1u)) >> 16;  // RNE
  return (short)r;
}

__device__ __forceinline__ void load_lds16(const void* g, void* l) {
  __builtin_amdgcn_global_load_lds(
      (const __attribute__((address_space(1))) uint32_t*)(uintptr_t)g,
      (__attribute__((address_space(3))) uint32_t*)(uint32_t)(uintptr_t)l,
      16, 0, 0);
}

// ---- 1. prep: x -> bf16 {x,x^2,x^3} (Xb), c1|c2|c3 -> bf16 Wb --------------
// bias skipped: a per-column constant shifts the batch mean and is cancelled
// exactly by BatchNorm (variance unaffected). [verified R6/R7]
__global__ void prep_all(const float4* __restrict__ x4,
                         const float4* __restrict__ c1, const float4* __restrict__ c2,
                         const float4* __restrict__ c3,
                         short* __restrict__ Xb, short* __restrict__ Wb) {
  int b = blockIdx.x;
  if (b < 4096) {
    int idx = b * 256 + threadIdx.x;           // 1,048,576 float4 of x
    float4 v = x4[idx];
    int row = idx >> 8;
    int c   = (idx & 255) << 2;
    size_t base = (size_t)row * KTOT + c;
    s4 p1 = { f2bf(v.x), f2bf(v.y), f2bf(v.z), f2bf(v.w) };
    float ax = v.x * v.x, ay = v.y * v.y, az = v.z * v.z, aw = v.w * v.w;
    s4 p2 = { f2bf(ax), f2bf(ay), f2bf(az), f2bf(aw) };
    s4 p3 = { f2bf(ax * v.x), f2bf(ay * v.y), f2bf(az * v.z), f2bf(aw * v.w) };
    *(s4*)&Xb[base]        = p1;
    *(s4*)&Xb[base + 1024] = p2;
    *(s4*)&Xb[base + 2048] = p3;
  } else {
    int idx = (b - 4096) * 256 + threadIdx.x;  // 262,144 float4 per weight
    int row = idx >> 8;
    int c   = (idx & 255) << 2;
    size_t base = (size_t)row * KTOT + c;
    float4 a = c1[idx], bb = c2[idx], d = c3[idx];
    s4 p1 = { f2bf(a.x),  f2bf(a.y),  f2bf(a.z),  f2bf(a.w)  };
    s4 p2 = { f2bf(bb.x), f2bf(bb.y), f2bf(bb.z), f2bf(bb.w) };
    s4 p3 = { f2bf(d.x),  f2bf(d.y),  f2bf(d.z),  f2bf(d.w)  };
    *(s4*)&Wb[base]        = p1;
    *(s4*)&Wb[base + 1024] = p2;
    *(s4*)&Wb[base + 2048] = p3;
  }
}

// ---- 2. GEMM 128x128, BK=64, QUAD-buffered LDS, 3-deep prefetch ------------
// Step s: s_waitcnt vmcnt(8) (own tile's 4 loads done; tiles s+1,s+2 = 8
// loads stay in flight) + raw s_barrier, then prefetch tile s+3 (12
// outstanding = 192 B/lane in flight). WAR safe: prefetch buf (s+3)%4 ==
// (s-1)%4, and the step-s barrier proves tile s-1 compute finished.
// LDS 4x(16+16) KB = 128 KB, 1 block/CU. XOR chunk swizzle: physical 16B
// slot p of row r holds logical chunk p ^ (r & 7) -> 0 conflicts [R2..R8].
__global__ __launch_bounds__(512, 2) void gemm_poly(
    const short* __restrict__ Xb, const short* __restrict__ Wb,
    float* __restrict__ Y, float* __restrict__ psum, float* __restrict__ psq) {
  __shared__ __align__(16) short As[4][BM * BK];   // 4 x 16 KB
  __shared__ __align__(16) short Bs[4][BN * BK];   // 4 x 16 KB  (128 KB total)
  const int tid  = threadIdx.x;
  const int lane = tid & 63;
  const int wave = tid >> 6;
  const int wr = wave >> 2;            // 0..1 : 64-row half
  const int wc = wave & 3;             // 0..3 : 32-col quarter
  const int lb  = blockIdx.x;
  const int xcd = lb & 7;
  const int sl  = lb >> 3;             // 0..31
  const int bx  = sl & 7;              // col-block 0..7
  const int by  = xcd * 4 + (sl >> 3); // row-strip 0..31
  const int row0 = by * BM;
  const int col0 = bx * BN;
  const short* Ag = Xb + (size_t)row0 * KTOT;
  const short* Bg = Wb + (size_t)col0 * KTOT;
  const int frag_m = lane & 15;
  const int sel = lane >> 4;           // k-quarter within a K=32 sub-step
  floatx4 acc[4][2] = {};

  // staging source offsets: 2 A-chunks + 2 B-chunks per thread
  int off01[2];
  #pragma unroll
  for (int i = 0; i < 2; ++i) {
    int c = tid + i * 512;
    int r = c >> 3, p = c & 7;
    int lg = p ^ (r & 7);
    off01[i] = r * KTOT + lg * 8;
  }

  // prologue: stage tiles 0,1,2 (4 load instrs per wave per tile, in order)
  #pragma unroll
  for (int t = 0; t < 3; ++t) {
    #pragma unroll
    for (int i = 0; i < 2; ++i) {
      load_lds16(Ag + off01[i] + t * BK, &As[t][(tid + i * 512) * 8]);
      load_lds16(Bg + off01[i] + t * BK, &Bs[t][(tid + i * 512) * 8]);
    }
  }

#define GSTEP(CUR, PRE, KT_PRE, DO_PRE, WAITIMM)                              \
  {                                                                           \
    __builtin_amdgcn_s_waitcnt(WAITIMM);                                      \
    __builtin_amdgcn_s_barrier();                                             \
    if (DO_PRE) {                                                             \
      _Pragma("unroll")                                                       \
      for (int i = 0; i < 2; ++i) {                                           \
        load_lds16(Ag + off01[i] + (KT_PRE), &As[PRE][(tid + i * 512) * 8]);  \
        load_lds16(Bg + off01[i] + (KT_PRE), &Bs[PRE][(tid + i * 512) * 8]);  \
      }                                                                       \
    }                                                                         \
    _Pragma("unroll")                                                         \
    for (int s = 0; s < 2; ++s) {                                             \
      short8 af[4], bfr[2];                                                   \
      _Pragma("unroll")                                                       \
      for (int i = 0; i < 4; ++i) {                                           \
        int r = wr * 64 + i * 16 + frag_m;                                    \
        int p = (s * 4 + sel) ^ (r & 7);                                      \
        af[i] = *(const short8*)&As[CUR][r * BK + p * 8];                     \
      }                                                                       \
      _Pragma("unroll")                                                       \
      for (int j = 0; j < 2; ++j) {                                           \
        int r = wc * 32 + j * 16 + frag_m;                                    \
        int p = (s * 4 + sel) ^ (r & 7);                                      \
        bfr[j] = *(const short8*)&Bs[CUR][r * BK + p * 8];                    \
      }                                                                       \
      _Pragma("unroll")                                                       \
      for (int i = 0; i < 4; ++i)                                             \
        _Pragma("unroll")                                                     \
        for (int j = 0; j < 2; ++j)                                           \
          acc[i][j] = __builtin_amdgcn_mfma_f32_16x16x32_bf16(                \
              af[i], bfr[j], acc[i][j], 0, 0, 0);                             \
    }                                                                         \
  }

  for (int t4 = 0; t4 < 44; t4 += 4) {         // steps 0..43
    GSTEP(0, 3, (t4 + 3) * BK, 1, WAIT_VM8);
    GSTEP(1, 0, (t4 + 4) * BK, 1, WAIT_VM8);
    GSTEP(2, 1, (t4 + 5) * BK, 1, WAIT_VM8);
    GSTEP(3, 2, (t4 + 6) * BK, 1, WAIT_VM8);
  }
  GSTEP(0, 3, 47 * BK, 1, WAIT_VM8);           // step 44, prefetch tile 47
  GSTEP(1, 0, 0, 0, WAIT_VM8);                 // step 45
  GSTEP(2, 0, 0, 0, WAIT_VM4);                 // step 46
  GSTEP(3, 0, 0, 0, WAIT_VM0);                 // step 47: drain everything
#undef GSTEP

  // epilogue: column sum/sumsq partials (no bias), un-normalized Y write
  float* colred = (float*)&As[0][0];   // [wr*256 + {0:sum,128:sq} + col], 2KB
  float sv[2] = {0.f, 0.f}, sq[2] = {0.f, 0.f};
  #pragma unroll
  for (int j = 0; j < 2; ++j)
    #pragma unroll
    for (int i = 0; i < 4; ++i)
      #pragma unroll
      for (int r = 0; r < 4; ++r) {
        float v = acc[i][j][r];
        sv[j] += v; sq[j] += v * v;
      }
  #pragma unroll
  for (int j = 0; j < 2; ++j) {        // fold 4 sel-groups sharing a column
    sv[j] += __shfl_xor(sv[j], 16, 64); sv[j] += __shfl_xor(sv[j], 32, 64);
    sq[j] += __shfl_xor(sq[j], 16, 64); sq[j] += __shfl_xor(sq[j], 32, 64);
  }
  if (sel == 0) {                      // As[0] dead since step 44's barrier
    #pragma unroll
    for (int j = 0; j < 2; ++j) {
      int cc = wc * 32 + j * 16 + frag_m;
      colred[wr * 256 + cc]       = sv[j];
      colred[wr * 256 + 128 + cc] = sq[j];
    }
  }
  // write Y (un-normalized) while colred settles
  const int drow = sel << 2;           // C/D: col=lane&15, row=(lane>>4)*4+r
  #pragma unroll
  for (int j = 0; j < 2; ++j) {
    int gc = col0 + wc * 32 + j * 16 + frag_m;
    #pragma unroll
    for (int i = 0; i < 4; ++i) {
      int gr = row0 + wr * 64 + i * 16 + drow;
      #pragma unroll
      for (int r = 0; r < 4; ++r)
        Y[(size_t)(gr + r) * OUTF + gc] = acc[i][j][r];
    }
  }
  __syncthreads();
  if (tid < BN) {
    psum[(size_t)by * OUTF + col0 + tid] = colred[tid]       + colred[256 + tid];
    psq [(size_t)by * OUTF + col0 + tid] = colred[128 + tid] + colred[384 + tid];
  }
}

// ---- 3. fused finalize + BN apply ------------------------------------------
__global__ void bn_fused(const float* __restrict__ psum, const float* __restrict__ psq,
                         const float* __restrict__ gamma, const float* __restrict__ beta,
                         float* __restrict__ Y) {
  __shared__ float sc[32], sh[32];
  const int c0 = blockIdx.x * 32;
  const int t = threadIdx.x;
  if (t < 32) {
    float s = 0.f, s2 = 0.f;
    #pragma unroll 8
    for (int p = 0; p < 32; ++p) {
      s  += psum[p * OUTF + c0 + t];
      s2 += psq [p * OUTF + c0 + t];
    }
    float mean = s * (1.0f / B_ROWS);
    float var  = s2 * (1.0f / B_ROWS) - mean * mean;
    float scale = gamma[c0 + t] * rsqrtf(var + BN_EPS);
    sc[t] = scale;
    sh[t] = beta[c0 + t] - mean * scale;
  }
  __syncthreads();
  const int f4c = t & 7;          // 8 float4 per 32-col slice
  const int rr  = t >> 3;         // 32 rows per sweep
  const int row0 = blockIdx.y * 256;
  float4* Y4 = (float4*)Y;
  const int cb = f4c * 4;
  float s0 = sc[cb], s1 = sc[cb+1], s2 = sc[cb+2], s3 = sc[cb+3];
  float h0 = sh[cb], h1 = sh[cb+1], h2 = sh[cb+2], h3 = sh[cb+3];
  #pragma unroll
  for (int it = 0; it < 8; ++it) {
    int row = row0 + it * 32 + rr;
    size_t idx = (size_t)row * 256 + (c0 >> 2) + f4c;
    float4 v = Y4[idx];
    v.x = v.x * s0 + h0; v.y = v.y * s1 + h1;
    v.z = v.z * s2 + h2; v.w = v.w * s3 + h3;
    Y4[idx] = v;
  }
}

extern "C" void kernel_launch(void* const* d_in, const int* in_sizes, int n_in,
                              void* d_out, int out_size, void* d_ws, size_t ws_size,
                              hipStream_t stream) {
  const float* x     = (const float*)d_in[0];
  const float* c1    = (const float*)d_in[1];
  const float* c2    = (const float*)d_in[2];
  const float* c3    = (const float*)d_in[3];
  // d_in[4] = bias: unused — per-column constant cancels exactly in BatchNorm
  const float* gamma = (const float*)d_in[5];
  const float* beta  = (const float*)d_in[6];
  float* out = (float*)d_out;
  char* ws = (char*)d_ws;

  short* Xb   = (short*)(ws);                          // 25,165,824 B
  short* Wb   = (short*)(ws + 25165824);               //  6,291,456 B
  float* psum = (float*)(ws + 31457280);               //    128 KB
  float* psq  = (float*)(ws + 31588352);               //    128 KB

  prep_all<<<5120, 256, 0, stream>>>((const float4*)x, (const float4*)c1,
                                     (const float4*)c2, (const float4*)c3,
                                     Xb, Wb);

  gemm_poly<<<256, 512, 0, stream>>>(Xb, Wb, out, psum, psq);

  dim3 bgrid(OUTF / 32, B_ROWS / 256);                 // (32, 16) = 512 blocks
  bn_fused<<<bgrid, 256, 0, stream>>>(psum, psq, gamma, beta, out);
}

// Round 10
// 124.118 us; speedup vs baseline: 1.0254x; 1.0105x over previous
//
#include <hip/hip_runtime.h>
#include <stdint.h>

#define B_ROWS 4096
#define OUTF   1024
#define INF    1024
#define KTOT   3072          // 3 * 1024
#define BN_EPS 1e-5f
#define BM 128
#define BN 128
#define BK 64
#define NSTEP (KTOT / BK)    // 48

typedef short  short8  __attribute__((ext_vector_type(8)));
typedef float  floatx4 __attribute__((ext_vector_type(4)));

struct alignas(8) s4 { short x, y, z, w; };

// s_waitcnt SIMM16 (gfx9/gfx950): vmcnt[3:0]=imm[3:0], expcnt=imm[6:4],
// lgkmcnt=imm[11:8], vmcnt[5:4]=imm[15:14].
#define WAIT_VM4 0x0F74      // vmcnt(4)
#define WAIT_VM2 0x0F72      // vmcnt(2)
#define WAIT_VM0 0x0F70      // vmcnt(0)

__device__ __forceinline__ short f2bf(float f) {
  union { float f; uint32_t u; } cv; cv.f = f;
  uint32_t u = cv.u;
  uint32_t r = (u + 0x7fffu + ((u >> 16) & 1u)) >> 16;  // RNE
  return (short)r;
}

__device__ __forceinline__ void load_lds16(const void* g, void* l) {
  __builtin_amdgcn_global_load_lds(
      (const __attribute__((address_space(1))) uint32_t*)(uintptr_t)g,
      (__attribute__((address_space(3))) uint32_t*)(uint32_t)(uintptr_t)l,
      16, 0, 0);
}

// ---- 1. prep: x -> bf16 {x,x^2,x^3} (Xb), c1|c2|c3 -> bf16 Wb --------------
// bias skipped: a per-column constant shifts the batch mean and is cancelled
// exactly by BatchNorm (variance unaffected). [verified R6..R9]
__global__ void prep_all(const float4* __restrict__ x4,
                         const float4* __restrict__ c1, const float4* __restrict__ c2,
                         const float4* __restrict__ c3,
                         short* __restrict__ Xb, short* __restrict__ Wb) {
  int b = blockIdx.x;
  if (b < 4096) {
    int idx = b * 256 + threadIdx.x;           // 1,048,576 float4 of x
    float4 v = x4[idx];
    int row = idx >> 8;
    int c   = (idx & 255) << 2;
    size_t base = (size_t)row * KTOT + c;
    s4 p1 = { f2bf(v.x), f2bf(v.y), f2bf(v.z), f2bf(v.w) };
    float ax = v.x * v.x, ay = v.y * v.y, az = v.z * v.z, aw = v.w * v.w;
    s4 p2 = { f2bf(ax), f2bf(ay), f2bf(az), f2bf(aw) };
    s4 p3 = { f2bf(ax * v.x), f2bf(ay * v.y), f2bf(az * v.z), f2bf(aw * v.w) };
    *(s4*)&Xb[base]        = p1;
    *(s4*)&Xb[base + 1024] = p2;
    *(s4*)&Xb[base + 2048] = p3;
  } else {
    int idx = (b - 4096) * 256 + threadIdx.x;  // 262,144 float4 per weight
    int row = idx >> 8;
    int c   = (idx & 255) << 2;
    size_t base = (size_t)row * KTOT + c;
    float4 a = c1[idx], bb = c2[idx], d = c3[idx];
    s4 p1 = { f2bf(a.x),  f2bf(a.y),  f2bf(a.z),  f2bf(a.w)  };
    s4 p2 = { f2bf(bb.x), f2bf(bb.y), f2bf(bb.z), f2bf(bb.w) };
    s4 p3 = { f2bf(d.x),  f2bf(d.y),  f2bf(d.z),  f2bf(d.w)  };
    *(s4*)&Wb[base]        = p1;
    *(s4*)&Wb[base + 1024] = p2;
    *(s4*)&Wb[base + 2048] = p3;
  }
}

// ---- 2. GEMM 128x128, BK=64, 1024 threads (16 waves), quad-buffer ----------
// 16 waves/CU = 2x the independent staging queues of R7..R9 (the inbound
// global->LDS rate tracked wave count in m97: 3 blk/CU -> 20 B/cyc/CU).
// Wave grid 4x4, each wave 32x32 (2x2 MFMA frags): LDS read traffic A*2+B*2
// = 96 KB/step (vs 128 for 2x4 geometry). Per thread: 1 A-chunk + 1 B-chunk
// per tile; 3-deep prefetch => 6 loads in flight, wait vmcnt(4) per step.
// LDS 4x(16+16) KB = 128 KB. XOR chunk swizzle: physical 16B slot p of row
// r holds logical chunk p ^ (r & 7) -> 0 conflicts [R2..R9].
__global__ __launch_bounds__(1024, 4) void gemm_poly(
    const short* __restrict__ Xb, const short* __restrict__ Wb,
    float* __restrict__ Y, float* __restrict__ psum, float* __restrict__ psq) {
  __shared__ __align__(16) short As[4][BM * BK];   // 4 x 16 KB
  __shared__ __align__(16) short Bs[4][BN * BK];   // 4 x 16 KB  (128 KB total)
  const int tid  = threadIdx.x;
  const int lane = tid & 63;
  const int wave = tid >> 6;           // 0..15
  const int wr = wave >> 2;            // 0..3 : 32-row group
  const int wc = wave & 3;             // 0..3 : 32-col group
  const int lb  = blockIdx.x;
  const int xcd = lb & 7;
  const int sl  = lb >> 3;             // 0..31
  const int bx  = sl & 7;              // col-block 0..7
  const int by  = xcd * 4 + (sl >> 3); // row-strip 0..31
  const int row0 = by * BM;
  const int col0 = bx * BN;
  const short* Ag = Xb + (size_t)row0 * KTOT;
  const short* Bg = Wb + (size_t)col0 * KTOT;
  const int frag_m = lane & 15;
  const int sel = lane >> 4;           // k-quarter within a K=32 sub-step
  floatx4 acc[2][2] = {};

  // staging: thread tid owns chunk tid of the A tile and chunk tid of the B
  // tile (1024 chunks of 16 B each). row r = tid>>3, slot p = tid&7,
  // logical source chunk l = p ^ (r & 7).
  const int soff = (tid >> 3) * KTOT + ((tid & 7) ^ ((tid >> 3) & 7)) * 8;
  const int ldst = tid * 8;

  // prologue: stage tiles 0,1,2 (2 loads per thread per tile, in order)
  #pragma unroll
  for (int t = 0; t < 3; ++t) {
    load_lds16(Ag + soff + t * BK, &As[t][ldst]);
    load_lds16(Bg + soff + t * BK, &Bs[t][ldst]);
  }

#define GSTEP(CUR, PRE, KT_PRE, DO_PRE, WAITIMM)                              \
  {                                                                           \
    __builtin_amdgcn_s_waitcnt(WAITIMM);                                      \
    __builtin_amdgcn_s_barrier();                                             \
    if (DO_PRE) {                                                             \
      load_lds16(Ag + soff + (KT_PRE), &As[PRE][ldst]);                       \
      load_lds16(Bg + soff + (KT_PRE), &Bs[PRE][ldst]);                       \
    }                                                                         \
    _Pragma("unroll")                                                         \
    for (int s = 0; s < 2; ++s) {                                             \
      short8 af[2], bfr[2];                                                   \
      _Pragma("unroll")                                                       \
      for (int i = 0; i < 2; ++i) {                                           \
        int r = wr * 32 + i * 16 + frag_m;                                    \
        int p = (s * 4 + sel) ^ (r & 7);                                      \
        af[i] = *(const short8*)&As[CUR][r * BK + p * 8];                     \
      }                                                                       \
      _Pragma("unroll")                                                       \
      for (int j = 0; j < 2; ++j) {                                           \
        int r = wc * 32 + j * 16 + frag_m;                                    \
        int p = (s * 4 + sel) ^ (r & 7);                                      \
        bfr[j] = *(const short8*)&Bs[CUR][r * BK + p * 8];                    \
      }                                                                       \
      _Pragma("unroll")                                                       \
      for (int i = 0; i < 2; ++i)                                             \
        _Pragma("unroll")                                                     \
        for (int j = 0; j < 2; ++j)                                           \
          acc[i][j] = __builtin_amdgcn_mfma_f32_16x16x32_bf16(                \
              af[i], bfr[j], acc[i][j], 0, 0, 0);                             \
    }                                                                         \
  }

  for (int t4 = 0; t4 < 44; t4 += 4) {         // steps 0..43 (prefetch s+3)
    GSTEP(0, 3, (t4 + 3) * BK, 1, WAIT_VM4);
    GSTEP(1, 0, (t4 + 4) * BK, 1, WAIT_VM4);
    GSTEP(2, 1, (t4 + 5) * BK, 1, WAIT_VM4);
    GSTEP(3, 2, (t4 + 6) * BK, 1, WAIT_VM4);
  }
  GSTEP(0, 3, 47 * BK, 1, WAIT_VM4);           // step 44, prefetch tile 47
  GSTEP(1, 0, 0, 0, WAIT_VM4);                 // step 45 (tiles 46,47 inflight)
  GSTEP(2, 0, 0, 0, WAIT_VM2);                 // step 46 (tile 47 in flight)
  GSTEP(3, 0, 0, 0, WAIT_VM0);                 // step 47: drain everything
#undef GSTEP

  // epilogue: column sum/sumsq partials (no bias), un-normalized Y write.
  // colred[4 wr-groups][sum|sq][128 cols] = 4 KB, aliased into As[0]
  // (dead: last read step 44; 3 barriers since).
  float* colred = (float*)&As[0][0];
  float sv[2] = {0.f, 0.f}, sq[2] = {0.f, 0.f};
  #pragma unroll
  for (int j = 0; j < 2; ++j)
    #pragma unroll
    for (int i = 0; i < 2; ++i)
      #pragma unroll
      for (int r = 0; r < 4; ++r) {
        float v = acc[i][j][r];
        sv[j] += v; sq[j] += v * v;
      }
  #pragma unroll
  for (int j = 0; j < 2; ++j) {        // fold 4 sel-groups sharing a column
    sv[j] += __shfl_xor(sv[j], 16, 64); sv[j] += __shfl_xor(sv[j], 32, 64);
    sq[j] += __shfl_xor(sq[j], 16, 64); sq[j] += __shfl_xor(sq[j], 32, 64);
  }
  if (sel == 0) {
    #pragma unroll
    for (int j = 0; j < 2; ++j) {
      int cc = wc * 32 + j * 16 + frag_m;
      colred[(wr * 2 + 0) * 128 + cc] = sv[j];
      colred[(wr * 2 + 1) * 128 + cc] = sq[j];
    }
  }
  // write Y (un-normalized) while colred settles
  #pragma unroll
  for (int j = 0; j < 2; ++j) {
    int gc = col0 + wc * 32 + j * 16 + frag_m;
    #pragma unroll
    for (int i = 0; i < 2; ++i) {
      int gr = row0 + wr * 32 + i * 16 + sel * 4;
      #pragma unroll
      for (int r = 0; r < 4; ++r)
        Y[(size_t)(gr + r) * OUTF + gc] = acc[i][j][r];
    }
  }
  __syncthreads();
  if (tid < BN) {
    float s0 = colred[0 * 128 + tid] + colred[2 * 128 + tid]
             + colred[4 * 128 + tid] + colred[6 * 128 + tid];
    float s1 = colred[1 * 128 + tid] + colred[3 * 128 + tid]
             + colred[5 * 128 + tid] + colred[7 * 128 + tid];
    psum[(size_t)by * OUTF + col0 + tid] = s0;
    psq [(size_t)by * OUTF + col0 + tid] = s1;
  }
}

// ---- 3. fused finalize + BN apply ------------------------------------------
__global__ void bn_fused(const float* __restrict__ psum, const float* __restrict__ psq,
                         const float* __restrict__ gamma, const float* __restrict__ beta,
                         float* __restrict__ Y) {
  __shared__ float sc[32], sh[32];
  const int c0 = blockIdx.x * 32;
  const int t = threadIdx.x;
  if (t < 32) {
    float s = 0.f, s2 = 0.f;
    #pragma unroll 8
    for (int p = 0; p < 32; ++p) {
      s  += psum[p * OUTF + c0 + t];
      s2 += psq [p * OUTF + c0 + t];
    }
    float mean = s * (1.0f / B_ROWS);
    float var  = s2 * (1.0f / B_ROWS) - mean * mean;
    float scale = gamma[c0 + t] * rsqrtf(var + BN_EPS);
    sc[t] = scale;
    sh[t] = beta[c0 + t] - mean * scale;
  }
  __syncthreads();
  const int f4c = t & 7;          // 8 float4 per 32-col slice
  const int rr  = t >> 3;         // 32 rows per sweep
  const int row0 = blockIdx.y * 256;
  float4* Y4 = (float4*)Y;
  const int cb = f4c * 4;
  float s0 = sc[cb], s1 = sc[cb+1], s2 = sc[cb+2], s3 = sc[cb+3];
  float h0 = sh[cb], h1 = sh[cb+1], h2 = sh[cb+2], h3 = sh[cb+3];
  #pragma unroll
  for (int it = 0; it < 8; ++it) {
    int row = row0 + it * 32 + rr;
    size_t idx = (size_t)row * 256 + (c0 >> 2) + f4c;
    float4 v = Y4[idx];
    v.x = v.x * s0 + h0; v.y = v.y * s1 + h1;
    v.z = v.z * s2 + h2; v.w = v.w * s3 + h3;
    Y4[idx] = v;
  }
}

extern "C" void kernel_launch(void* const* d_in, const int* in_sizes, int n_in,
                              void* d_out, int out_size, void* d_ws, size_t ws_size,
                              hipStream_t stream) {
  const float* x     = (const float*)d_in[0];
  const float* c1    = (const float*)d_in[1];
  const float* c2    = (const float*)d_in[2];
  const float* c3    = (const float*)d_in[3];
  // d_in[4] = bias: unused — per-column constant cancels exactly in BatchNorm
  const float* gamma = (const float*)d_in[5];
  const float* beta  = (const float*)d_in[6];
  float* out = (float*)d_out;
  char* ws = (char*)d_ws;

  short* Xb   = (short*)(ws);                          // 25,165,824 B
  short* Wb   = (short*)(ws + 25165824);               //  6,291,456 B
  float* psum = (float*)(ws + 31457280);               //    128 KB
  float* psq  = (float*)(ws + 31588352);               //    128 KB

  prep_all<<<5120, 256, 0, stream>>>((const float4*)x, (const float4*)c1,
                                     (const float4*)c2, (const float4*)c3,
                                     Xb, Wb);

  gemm_poly<<<256, 1024, 0, stream>>>(Xb, Wb, out, psum, psq);

  dim3 bgrid(OUTF / 32, B_ROWS / 256);                 // (32, 16) = 512 blocks
  bn_fused<<<bgrid, 256, 0, stream>>>(psum, psq, gamma, beta, out);
}